// Round 8
// baseline (760.717 us; speedup 1.0000x reference)
//
#include <hip/hip_runtime.h>

#define N_NODES 100000
#define N_EDGES 1600000
#define PAD 48
#define NB 391                  // ceil(N_NODES/256) dst-buckets
#define NBLK 256                // partition blocks
#define EPB (N_EDGES / NBLK)    // 6250 edges per block (exact)
#define SCAN_N (NB * NBLK)      // 100096
#define AGG_GRID 2048

using bf16x8 = __attribute__((ext_vector_type(8))) short;
using f32x4  = __attribute__((ext_vector_type(4))) float;

// ---------------- bf16 helpers ----------------

__device__ __forceinline__ float bflo(unsigned u) { return __uint_as_float(u << 16); }
__device__ __forceinline__ float bfhi(unsigned u) { return __uint_as_float(u & 0xffff0000u); }
__device__ __forceinline__ unsigned packbf(float a, float b) {
    unsigned ua = __float_as_uint(a), ub = __float_as_uint(b);
    ua = ua + 0x7fffu + ((ua >> 16) & 1u);
    ub = ub + 0x7fffu + ((ub >> 16) & 1u);
    return (ua >> 16) | (ub & 0xffff0000u);
}

// ---------------- edge partition (no global atomics) ----------------

// phase A: per-block bucket histogram (LDS atomics only)
__global__ __launch_bounds__(256) void hist_kernel(const int* __restrict__ dst,
                                                   int* __restrict__ counts) {
    __shared__ int hist[NB];
    int tid = threadIdx.x, blk = blockIdx.x;
    for (int i = tid; i < NB; i += 256) hist[i] = 0;
    __syncthreads();
    int s0 = blk * EPB;
    for (int k = tid; k < EPB; k += 256)
        atomicAdd(&hist[dst[s0 + k] >> 8], 1);
    __syncthreads();
    for (int b = tid; b < NB; b += 256) counts[b * NBLK + blk] = hist[b];
}

// 3-phase exclusive scan over counts[SCAN_N] -> off[SCAN_N+1]
__global__ __launch_bounds__(1024) void scan1_kernel(const int* __restrict__ cnt,
                                                     int* __restrict__ off,
                                                     int* __restrict__ bsum, int n) {
    __shared__ int wsum[17];
    int tid = threadIdx.x, lane = tid & 63, w = tid >> 6;
    int i = blockIdx.x * 1024 + tid;
    int v = (i < n) ? cnt[i] : 0;
    int x = v;
    #pragma unroll
    for (int d = 1; d < 64; d <<= 1) {
        int y = __shfl_up(x, d, 64);
        if (lane >= d) x += y;
    }
    if (lane == 63) wsum[w] = x;
    __syncthreads();
    if (tid == 0) {
        int s = 0;
        #pragma unroll
        for (int j = 0; j < 16; j++) { int t = wsum[j]; wsum[j] = s; s += t; }
        wsum[16] = s;
    }
    __syncthreads();
    if (i < n) off[i + 1] = x + wsum[w];
    if (tid == 0) bsum[blockIdx.x] = wsum[16];
}

// also zeroes BN stats arrays and finalize counters (saves separate launches)
__global__ void scan2_kernel(int* __restrict__ bsum, int nb, float* __restrict__ stats1,
                             float* __restrict__ stats2, int* __restrict__ ctr) {
    int t = threadIdx.x;  // 256
    stats1[t] = 0.f;
    stats2[t] = 0.f;
    if (t < 2) ctr[t] = 0;
    if (t == 0) {
        int s = 0;
        for (int j = 0; j < nb; j++) { int v = bsum[j]; bsum[j] = s; s += v; }
    }
}

__global__ __launch_bounds__(1024) void scan3_kernel(int* __restrict__ off,
                                                     const int* __restrict__ bsum, int n) {
    int i = blockIdx.x * 1024 + threadIdx.x;
    if (i < n) off[i + 1] += bsum[blockIdx.x];
    if (i == 0) off[0] = 0;
}

// phase C: scatter edges into bucket-major ebuf; runs are contiguous & single-writer
__global__ __launch_bounds__(256) void part_kernel(const int* __restrict__ src,
                                                   const int* __restrict__ dst,
                                                   const int* __restrict__ off,
                                                   int2* __restrict__ ebuf) {
    __shared__ int cur[NB];
    int tid = threadIdx.x, blk = blockIdx.x;
    for (int b = tid; b < NB; b += 256) cur[b] = off[b * NBLK + blk];
    __syncthreads();
    int s0 = blk * EPB;
    for (int k = tid; k < EPB; k += 256) {
        int s = src[s0 + k], d = dst[s0 + k];
        int pos = atomicAdd(&cur[d >> 8], 1);
        ebuf[pos] = make_int2(s, d);
    }
}

// phase D: one block per bucket; build padded-CSR slab in LDS, coalesced copy out.
// Also emits dinv (true degree known in cur[]).
__global__ __launch_bounds__(256) void bucket_kernel(const int2* __restrict__ ebuf,
                                                     const int* __restrict__ off,
                                                     int* __restrict__ esrc_pad,
                                                     int* __restrict__ cnt,
                                                     float* __restrict__ dinv, int n) {
    __shared__ int epad[256 * PAD];
    __shared__ int cur[256];
    int tid = threadIdx.x, b = blockIdx.x;
    int start = off[b * NBLK], end = off[(b + 1) * NBLK];
    cur[tid] = 0;
    __syncthreads();
    for (int e = start + tid; e < end; e += 256) {
        int2 sd = ebuf[e];
        int ld = sd.y & 255;
        int pos = atomicAdd(&cur[ld], 1);
        if (pos < PAD) epad[ld * PAD + pos] = sd.x;
    }
    __syncthreads();
    int nd0 = b << 8;
    int nn = min(256, n - nd0);
    if (tid < nn) {
        cnt[nd0 + tid] = cur[tid];
        dinv[nd0 + tid] = rsqrtf((float)(cur[tid] + 1));  // +1 self-loop
    }
    int tot = nn * PAD;
    for (int i = tid; i < tot; i += 256) esrc_pad[(size_t)nd0 * PAD + i] = epad[i];
}

// ---------------- weight transpose+convert (all 3 in one launch) ----------------

__global__ void wconv3_kernel(const float* __restrict__ W1, const float* __restrict__ W2,
                              const float* __restrict__ W3, unsigned* __restrict__ Wt1,
                              unsigned* __restrict__ Wt2, unsigned* __restrict__ Wt3) {
    int b = blockIdx.x;
    const float* W;
    unsigned* Wt;
    int M, i;
    if (b < 32)      { W = W1; Wt = Wt1; M = 128; i = b * 256 + threadIdx.x; }
    else if (b < 64) { W = W2; Wt = Wt2; M = 128; i = (b - 32) * 256 + threadIdx.x; }
    else             { W = W3; Wt = Wt3; M = 64;  i = (b - 64) * 256 + threadIdx.x; }
    if (i >= M * 64) return;
    int m = i >> 6, ku = i & 63;
    Wt[(size_t)m * 64 + ku] = packbf(W[(size_t)(2 * ku) * M + m], W[(size_t)(2 * ku + 1) * M + m]);
}

// ---------------- MFMA GEMM: H[n,M](bf16) = act(X[n,128]) @ W[128,M] ----------------

template <int M, int MODE>
__global__ __launch_bounds__(256) void gemm_mfma_kernel(const void* __restrict__ Xv,
                                                        const unsigned* __restrict__ Wt,
                                                        const float* __restrict__ ss,
                                                        unsigned* __restrict__ H, int n) {
    int wid = threadIdx.x >> 6, lane = threadIdx.x & 63;
    int r0 = (blockIdx.x * 4 + wid) * 16;
    if (r0 >= n) return;
    int rl = lane & 15, kg = lane >> 4;
    int row = r0 + rl;

    bf16x8 xf[4];
    if constexpr (MODE == 0) {
        const float* X = (const float*)Xv;
        #pragma unroll
        for (int ks = 0; ks < 4; ks++) {
            const float* p = &X[(size_t)row * 128 + ks * 32 + kg * 8];
            float4 f0 = *(const float4*)p;
            float4 f1 = *(const float4*)(p + 4);
            unsigned o[4] = { packbf(f0.x, f0.y), packbf(f0.z, f0.w),
                              packbf(f1.x, f1.y), packbf(f1.z, f1.w) };
            xf[ks] = *(bf16x8*)o;
        }
    } else {
        const unsigned* X = (const unsigned*)Xv;
        #pragma unroll
        for (int ks = 0; ks < 4; ks++) {
            int c = ks * 32 + kg * 8;
            uint4 u = *(const uint4*)&X[(size_t)row * 64 + (c >> 1)];
            float4 sc0 = *(const float4*)&ss[c];
            float4 sc1 = *(const float4*)&ss[c + 4];
            float4 sh0 = *(const float4*)&ss[128 + c];
            float4 sh1 = *(const float4*)&ss[128 + c + 4];
            float v0 = fmaxf(bflo(u.x) * sc0.x + sh0.x, 0.f);
            float v1 = fmaxf(bfhi(u.x) * sc0.y + sh0.y, 0.f);
            float v2 = fmaxf(bflo(u.y) * sc0.z + sh0.z, 0.f);
            float v3 = fmaxf(bfhi(u.y) * sc0.w + sh0.w, 0.f);
            float v4 = fmaxf(bflo(u.z) * sc1.x + sh1.x, 0.f);
            float v5 = fmaxf(bfhi(u.z) * sc1.y + sh1.y, 0.f);
            float v6 = fmaxf(bflo(u.w) * sc1.z + sh1.z, 0.f);
            float v7 = fmaxf(bfhi(u.w) * sc1.w + sh1.w, 0.f);
            unsigned o[4] = { packbf(v0, v1), packbf(v2, v3), packbf(v4, v5), packbf(v6, v7) };
            xf[ks] = *(bf16x8*)o;
        }
    }

    constexpr int NCB = M / 16;
    f32x4 acc[NCB];
    #pragma unroll
    for (int cb = 0; cb < NCB; cb++) acc[cb] = (f32x4){0.f, 0.f, 0.f, 0.f};

    #pragma unroll
    for (int cb = 0; cb < NCB; cb++) {
        #pragma unroll
        for (int ks = 0; ks < 4; ks++) {
            bf16x8 wf = *(const bf16x8*)&Wt[(size_t)(cb * 16 + rl) * 64 + ks * 16 + kg * 4];
            acc[cb] = __builtin_amdgcn_mfma_f32_16x16x32_bf16(wf, xf[ks], acc[cb], 0, 0, 0);
        }
    }

    unsigned* Hrow = &H[(size_t)row * (M / 2)];
    #pragma unroll
    for (int cb = 0; cb < NCB; cb++) {
        uint2 o;
        o.x = packbf(acc[cb][0], acc[cb][1]);
        o.y = packbf(acc[cb][2], acc[cb][3]);
        *(uint2*)&Hrow[cb * 8 + kg * 2] = o;
    }
}

// ---------------- aggregation + fused BN stats/scale (grid-stride, last-block finalize) ----

__global__ __launch_bounds__(256) void agg128bn_kernel(const unsigned* __restrict__ H,
                                                       const int* __restrict__ cnt,
                                                       const int* __restrict__ esrc_pad,
                                                       const float* __restrict__ dinv,
                                                       const float* __restrict__ bias,
                                                       unsigned* __restrict__ out,
                                                       float* __restrict__ stats,
                                                       float* __restrict__ ss,
                                                       const float* __restrict__ g,
                                                       const float* __restrict__ be,
                                                       int* __restrict__ counter, int n) {
    int lane = threadIdx.x & 63;
    int wv = threadIdx.x >> 6;
    int gw = blockIdx.x * 4 + wv;            // global wave id, AGG_GRID*4 total
    float2 b = *(const float2*)&bias[lane * 2];
    float s0 = 0.f, s1 = 0.f, q0 = 0.f, q1 = 0.f;
    for (int node = gw; node < n; node += AGG_GRID * 4) {
        float dn = dinv[node];
        int c = min(cnt[node], PAD);
        int s_l = (lane < c) ? esrc_pad[(size_t)node * PAD + lane] : node;
        float w_l = (lane < c) ? dinv[s_l] * dn : 0.f;
        unsigned u0 = H[(size_t)node * 64 + lane];
        float acc0 = dn * dn * bflo(u0), acc1 = dn * dn * bfhi(u0);
        for (int j = 0; j < c; j += 16) {
            unsigned u[16];
            int sr[16];
            float wr[16];
            #pragma unroll
            for (int t = 0; t < 16; t++) {
                sr[t] = __builtin_amdgcn_readlane(s_l, j + t);
                wr[t] = __uint_as_float(__builtin_amdgcn_readlane(__float_as_uint(w_l), j + t));
                u[t] = H[(size_t)sr[t] * 64 + lane];
            }
            #pragma unroll
            for (int t = 0; t < 16; t++) {
                acc0 += wr[t] * bflo(u[t]);
                acc1 += wr[t] * bfhi(u[t]);
            }
        }
        float o0 = acc0 + b.x, o1 = acc1 + b.y;
        out[(size_t)node * 64 + lane] = packbf(o0, o1);
        s0 += o0; q0 += o0 * o0;
        s1 += o1; q1 += o1 * o1;
    }
    // block-level BN partial reduction
    __shared__ float ls[4][128], lq[4][128];
    ls[wv][lane * 2] = s0; ls[wv][lane * 2 + 1] = s1;
    lq[wv][lane * 2] = q0; lq[wv][lane * 2 + 1] = q1;
    __syncthreads();
    int tid = threadIdx.x;
    if (tid < 128) {
        float s = ls[0][tid] + ls[1][tid] + ls[2][tid] + ls[3][tid];
        float q = lq[0][tid] + lq[1][tid] + lq[2][tid] + lq[3][tid];
        atomicAdd(&stats[tid], s);
        atomicAdd(&stats[128 + tid], q);
    }
    __syncthreads();            // drains this block's atomics (vmcnt(0) before barrier)
    __threadfence();
    __shared__ int isLast;
    if (tid == 0) isLast = (atomicAdd(counter, 1) == (int)gridDim.x - 1);
    __syncthreads();
    if (isLast && tid < 128) {
        float s = atomicAdd(&stats[tid], 0.f);         // device-coherent read
        float q = atomicAdd(&stats[128 + tid], 0.f);
        float inv_n = 1.f / (float)n;
        float mu = s * inv_n;
        float var = q * inv_n - mu * mu;
        float sc = g[tid] * rsqrtf(var + 1e-5f);
        ss[tid] = sc;
        ss[128 + tid] = be[tid] - mu * sc;
    }
}

__global__ __launch_bounds__(256) void agg64_kernel(const unsigned short* __restrict__ H,
                                                    const int* __restrict__ cnt,
                                                    const int* __restrict__ esrc_pad,
                                                    const float* __restrict__ dinv,
                                                    const float* __restrict__ bias,
                                                    float* __restrict__ out, int n) {
    int node = (blockIdx.x * blockDim.x + threadIdx.x) >> 6;
    int lane = threadIdx.x & 63;
    if (node >= n) return;
    float dn = dinv[node];
    float bb = bias[lane];
    int c = min(cnt[node], PAD);
    int s_l = (lane < c) ? esrc_pad[(size_t)node * PAD + lane] : node;
    float w_l = (lane < c) ? dinv[s_l] * dn : 0.f;
    float acc = dn * dn * __uint_as_float(((unsigned)H[(size_t)node * 64 + lane]) << 16);
    for (int j = 0; j < c; j += 16) {
        unsigned short u[16];
        int sr[16];
        float wr[16];
        #pragma unroll
        for (int t = 0; t < 16; t++) {
            sr[t] = __builtin_amdgcn_readlane(s_l, j + t);
            wr[t] = __uint_as_float(__builtin_amdgcn_readlane(__float_as_uint(w_l), j + t));
            u[t] = H[(size_t)sr[t] * 64 + lane];
        }
        #pragma unroll
        for (int t = 0; t < 16; t++) {
            acc += wr[t] * __uint_as_float(((unsigned)u[t]) << 16);
        }
    }
    out[(size_t)node * 64 + lane] = acc + bb;
}

// ---------------- launch ----------------

extern "C" void kernel_launch(void* const* d_in, const int* in_sizes, int n_in,
                              void* d_out, int out_size, void* d_ws, size_t ws_size,
                              hipStream_t stream) {
    const float* x  = (const float*)d_in[0];
    const int*   ei = (const int*)d_in[1];
    const float* W1 = (const float*)d_in[2];
    const float* b1 = (const float*)d_in[3];
    const float* g1 = (const float*)d_in[4];
    const float* be1 = (const float*)d_in[5];
    const float* W2 = (const float*)d_in[6];
    const float* b2 = (const float*)d_in[7];
    const float* g2 = (const float*)d_in[8];
    const float* be2 = (const float*)d_in[9];
    const float* W3 = (const float*)d_in[10];
    const float* b3 = (const float*)d_in[11];
    float* out = (float*)d_out;

    const int n = N_NODES, E = N_EDGES;
    const int* src = ei;
    const int* dst = ei + E;
    const int gemmGrid = (n + 63) / 64;
    const int nbScan = (SCAN_N + 1023) / 1024;

    char* p = (char*)d_ws;
    auto alloc = [&](size_t bytes) {
        void* r = (void*)p;
        p += (bytes + 255) & ~(size_t)255;
        return r;
    };
    int*      counts   = (int*)alloc((size_t)SCAN_N * 4);
    int*      off      = (int*)alloc((size_t)(SCAN_N + 1) * 4);
    int*      bsum     = (int*)alloc((size_t)nbScan * 4);
    int2*     ebuf     = (int2*)alloc((size_t)E * 8);
    int*      cnt      = (int*)alloc((size_t)n * 4);
    float*    dinv     = (float*)alloc((size_t)n * 4);
    int*      esrc_pad = (int*)alloc((size_t)n * PAD * 4);
    unsigned* Hb       = (unsigned*)alloc((size_t)n * 64 * 4);
    unsigned* Ab       = (unsigned*)alloc((size_t)n * 64 * 4);
    unsigned* Wt1      = (unsigned*)alloc(128 * 64 * 4);
    unsigned* Wt2      = (unsigned*)alloc(128 * 64 * 4);
    unsigned* Wt3      = (unsigned*)alloc(64 * 64 * 4);
    float*    stats1   = (float*)alloc(256 * 4);
    float*    stats2   = (float*)alloc(256 * 4);
    float*    ss1      = (float*)alloc(256 * 4);
    float*    ss2      = (float*)alloc(256 * 4);
    int*      ctr      = (int*)alloc(2 * 4);

    // edge partition: LDS-atomic multisplit, no global atomics
    hist_kernel<<<NBLK, 256, 0, stream>>>(dst, counts);
    scan1_kernel<<<nbScan, 1024, 0, stream>>>(counts, off, bsum, SCAN_N);
    scan2_kernel<<<1, 256, 0, stream>>>(bsum, nbScan, stats1, stats2, ctr);
    scan3_kernel<<<nbScan, 1024, 0, stream>>>(off, bsum, SCAN_N);
    part_kernel<<<NBLK, 256, 0, stream>>>(src, dst, off, ebuf);
    bucket_kernel<<<NB, 256, 0, stream>>>(ebuf, off, esrc_pad, cnt, dinv, n);

    // weights -> bf16 transposed (single launch)
    wconv3_kernel<<<80, 256, 0, stream>>>(W1, W2, W3, Wt1, Wt2, Wt3);

    // layer 1 (agg fuses BN1 stats + scale finalize)
    gemm_mfma_kernel<128, 0><<<gemmGrid, 256, 0, stream>>>(x, Wt1, nullptr, Hb, n);
    agg128bn_kernel<<<AGG_GRID, 256, 0, stream>>>(Hb, cnt, esrc_pad, dinv, b1, Ab,
                                                  stats1, ss1, g1, be1, &ctr[0], n);

    // layer 2 (BN1+ReLU fused into GEMM A-load; agg fuses BN2)
    gemm_mfma_kernel<128, 1><<<gemmGrid, 256, 0, stream>>>(Ab, Wt2, ss1, Hb, n);
    agg128bn_kernel<<<AGG_GRID, 256, 0, stream>>>(Hb, cnt, esrc_pad, dinv, b2, Ab,
                                                  stats2, ss2, g2, be2, &ctr[1], n);

    // layer 3 (BN2+ReLU fused; bias b3 in agg; fp32 out)
    gemm_mfma_kernel<64, 1><<<gemmGrid, 256, 0, stream>>>(Ab, Wt3, ss2, Hb, n);
    agg64_kernel<<<n / 4, 256, 0, stream>>>((const unsigned short*)Hb, cnt, esrc_pad, dinv, b3, out, n);
}

// Round 9
// 364.826 us; speedup vs baseline: 2.0851x; 2.0851x over previous
//
#include <hip/hip_runtime.h>

#define N_NODES 100000
#define N_EDGES 1600000
#define PAD 48
#define NB 391                  // ceil(N_NODES/256) dst-buckets
#define NBLK 256                // partition blocks
#define EPB (N_EDGES / NBLK)    // 6250 edges per block (exact)
#define SCAN_N (NB * NBLK)      // 100096

using bf16x8 = __attribute__((ext_vector_type(8))) short;
using f32x4  = __attribute__((ext_vector_type(4))) float;

// ---------------- bf16 helpers ----------------

__device__ __forceinline__ float bflo(unsigned u) { return __uint_as_float(u << 16); }
__device__ __forceinline__ float bfhi(unsigned u) { return __uint_as_float(u & 0xffff0000u); }
__device__ __forceinline__ unsigned packbf(float a, float b) {
    unsigned ua = __float_as_uint(a), ub = __float_as_uint(b);
    ua = ua + 0x7fffu + ((ua >> 16) & 1u);
    ub = ub + 0x7fffu + ((ub >> 16) & 1u);
    return (ua >> 16) | (ub & 0xffff0000u);
}

// ---------------- edge partition (no global atomics) ----------------

// phase A: per-block bucket histogram (LDS atomics only)
__global__ __launch_bounds__(256) void hist_kernel(const int* __restrict__ dst,
                                                   int* __restrict__ counts) {
    __shared__ int hist[NB];
    int tid = threadIdx.x, blk = blockIdx.x;
    for (int i = tid; i < NB; i += 256) hist[i] = 0;
    __syncthreads();
    int s0 = blk * EPB;
    for (int k = tid; k < EPB; k += 256)
        atomicAdd(&hist[dst[s0 + k] >> 8], 1);
    __syncthreads();
    for (int b = tid; b < NB; b += 256) counts[b * NBLK + blk] = hist[b];
}

// scan phase 1: per-block inclusive scan; off_raw[i+1] = partial, bsum[blk] = block total
__global__ __launch_bounds__(1024) void scan1_kernel(const int* __restrict__ cnt,
                                                     int* __restrict__ off,
                                                     int* __restrict__ bsum, int n) {
    __shared__ int wsum[17];
    int tid = threadIdx.x, lane = tid & 63, w = tid >> 6;
    int i = blockIdx.x * 1024 + tid;
    int v = (i < n) ? cnt[i] : 0;
    int x = v;
    #pragma unroll
    for (int d = 1; d < 64; d <<= 1) {
        int y = __shfl_up(x, d, 64);
        if (lane >= d) x += y;
    }
    if (lane == 63) wsum[w] = x;
    __syncthreads();
    if (tid == 0) {
        int s = 0;
        #pragma unroll
        for (int j = 0; j < 16; j++) { int t = wsum[j]; wsum[j] = s; s += t; }
        wsum[16] = s;
    }
    __syncthreads();
    if (i < n) off[i + 1] = x + wsum[w];
    if (tid == 0) bsum[blockIdx.x] = wsum[16];
}

// scan phase 2: serial scan of 98 block sums; also zeroes BN stats arrays
__global__ void scan2_kernel(int* __restrict__ bsum, int nb, float* __restrict__ stats1,
                             float* __restrict__ stats2) {
    int t = threadIdx.x;  // 256
    stats1[t] = 0.f;
    stats2[t] = 0.f;
    if (t == 0) {
        int s = 0;
        for (int j = 0; j < nb; j++) { int v = bsum[j]; bsum[j] = s; s += v; }
    }
}

__device__ __forceinline__ int off_at(const int* __restrict__ off_raw,
                                      const int* __restrict__ bsum, int idx) {
    return idx ? off_raw[idx] + bsum[(idx - 1) >> 10] : 0;
}

// phase C: scatter edges into bucket-major ebuf (packed: src | local_dst<<17)
__global__ __launch_bounds__(256) void part_kernel(const int* __restrict__ src,
                                                   const int* __restrict__ dst,
                                                   const int* __restrict__ off_raw,
                                                   const int* __restrict__ bsum,
                                                   unsigned* __restrict__ ebuf) {
    __shared__ int cur[NB];
    int tid = threadIdx.x, blk = blockIdx.x;
    for (int b = tid; b < NB; b += 256)
        cur[b] = off_at(off_raw, bsum, b * NBLK + blk);
    __syncthreads();
    int s0 = blk * EPB;
    for (int k = tid; k < EPB; k += 256) {
        int s = src[s0 + k], d = dst[s0 + k];
        int pos = atomicAdd(&cur[d >> 8], 1);
        ebuf[pos] = (unsigned)s | ((unsigned)(d & 255) << 17);
    }
}

// phase D: one block per bucket; build padded-CSR slab in LDS, coalesced copy out.
__global__ __launch_bounds__(256) void bucket_kernel(const unsigned* __restrict__ ebuf,
                                                     const int* __restrict__ off_raw,
                                                     const int* __restrict__ bsum,
                                                     int* __restrict__ esrc_pad,
                                                     int* __restrict__ cnt,
                                                     float* __restrict__ dinv, int n) {
    __shared__ int epad[256 * PAD];
    __shared__ int cur[256];
    int tid = threadIdx.x, b = blockIdx.x;
    int start = off_at(off_raw, bsum, b * NBLK);
    int end = off_at(off_raw, bsum, (b + 1) * NBLK);
    cur[tid] = 0;
    __syncthreads();
    for (int e = start + tid; e < end; e += 256) {
        unsigned sd = ebuf[e];
        int ld = sd >> 17;
        int pos = atomicAdd(&cur[ld], 1);
        if (pos < PAD) epad[ld * PAD + pos] = (int)(sd & 0x1FFFFu);
    }
    __syncthreads();
    int nd0 = b << 8;
    int nn = min(256, n - nd0);
    if (tid < nn) {
        cnt[nd0 + tid] = cur[tid];
        dinv[nd0 + tid] = rsqrtf((float)(cur[tid] + 1));  // +1 self-loop
    }
    int tot = nn * PAD;
    for (int i = tid; i < tot; i += 256) esrc_pad[(size_t)nd0 * PAD + i] = epad[i];
}

// ---------------- weight transpose+convert (all 3 in one launch) ----------------

__global__ void wconv3_kernel(const float* __restrict__ W1, const float* __restrict__ W2,
                              const float* __restrict__ W3, unsigned* __restrict__ Wt1,
                              unsigned* __restrict__ Wt2, unsigned* __restrict__ Wt3) {
    int b = blockIdx.x;
    const float* W;
    unsigned* Wt;
    int M, i;
    if (b < 32)      { W = W1; Wt = Wt1; M = 128; i = b * 256 + threadIdx.x; }
    else if (b < 64) { W = W2; Wt = Wt2; M = 128; i = (b - 32) * 256 + threadIdx.x; }
    else             { W = W3; Wt = Wt3; M = 64;  i = (b - 64) * 256 + threadIdx.x; }
    if (i >= M * 64) return;
    int m = i >> 6, ku = i & 63;
    Wt[(size_t)m * 64 + ku] = packbf(W[(size_t)(2 * ku) * M + m], W[(size_t)(2 * ku + 1) * M + m]);
}

// ---------------- MFMA GEMM: H[n,M](bf16) = act(X[n,128]) @ W[128,M] ----------------
// MODE 0: X fp32, no BN. MODE 1: X bf16 + fused BN+ReLU; sc/sh computed in-block
// from raw stats (folds the bnscale kernel into the GEMM).

template <int M, int MODE>
__global__ __launch_bounds__(256) void gemm_mfma_kernel(const void* __restrict__ Xv,
                                                        const unsigned* __restrict__ Wt,
                                                        const float* __restrict__ stats,
                                                        const float* __restrict__ g,
                                                        const float* __restrict__ be,
                                                        unsigned* __restrict__ H, int n) {
    __shared__ float sls[256];  // [0:128) scale, [128:256) shift
    if constexpr (MODE == 1) {
        int t = threadIdx.x;
        if (t < 128) {
            float inv_n = 1.f / (float)n;
            float mu = stats[t] * inv_n;
            float var = stats[128 + t] * inv_n - mu * mu;
            float sc = g[t] * rsqrtf(var + 1e-5f);
            sls[t] = sc;
            sls[128 + t] = be[t] - mu * sc;
        }
        __syncthreads();
    }
    int wid = threadIdx.x >> 6, lane = threadIdx.x & 63;
    int r0 = (blockIdx.x * 4 + wid) * 16;
    if (r0 >= n) return;
    int rl = lane & 15, kg = lane >> 4;
    int row = r0 + rl;

    bf16x8 xf[4];
    if constexpr (MODE == 0) {
        const float* X = (const float*)Xv;
        #pragma unroll
        for (int ks = 0; ks < 4; ks++) {
            const float* p = &X[(size_t)row * 128 + ks * 32 + kg * 8];
            float4 f0 = *(const float4*)p;
            float4 f1 = *(const float4*)(p + 4);
            unsigned o[4] = { packbf(f0.x, f0.y), packbf(f0.z, f0.w),
                              packbf(f1.x, f1.y), packbf(f1.z, f1.w) };
            xf[ks] = *(bf16x8*)o;
        }
    } else {
        const unsigned* X = (const unsigned*)Xv;
        #pragma unroll
        for (int ks = 0; ks < 4; ks++) {
            int c = ks * 32 + kg * 8;
            uint4 u = *(const uint4*)&X[(size_t)row * 64 + (c >> 1)];
            float4 sc0 = *(const float4*)&sls[c];
            float4 sc1 = *(const float4*)&sls[c + 4];
            float4 sh0 = *(const float4*)&sls[128 + c];
            float4 sh1 = *(const float4*)&sls[128 + c + 4];
            float v0 = fmaxf(bflo(u.x) * sc0.x + sh0.x, 0.f);
            float v1 = fmaxf(bfhi(u.x) * sc0.y + sh0.y, 0.f);
            float v2 = fmaxf(bflo(u.y) * sc0.z + sh0.z, 0.f);
            float v3 = fmaxf(bfhi(u.y) * sc0.w + sh0.w, 0.f);
            float v4 = fmaxf(bflo(u.z) * sc1.x + sh1.x, 0.f);
            float v5 = fmaxf(bfhi(u.z) * sc1.y + sh1.y, 0.f);
            float v6 = fmaxf(bflo(u.w) * sc1.z + sh1.z, 0.f);
            float v7 = fmaxf(bfhi(u.w) * sc1.w + sh1.w, 0.f);
            unsigned o[4] = { packbf(v0, v1), packbf(v2, v3), packbf(v4, v5), packbf(v6, v7) };
            xf[ks] = *(bf16x8*)o;
        }
    }

    constexpr int NCB = M / 16;
    f32x4 acc[NCB];
    #pragma unroll
    for (int cb = 0; cb < NCB; cb++) acc[cb] = (f32x4){0.f, 0.f, 0.f, 0.f};

    #pragma unroll
    for (int cb = 0; cb < NCB; cb++) {
        #pragma unroll
        for (int ks = 0; ks < 4; ks++) {
            bf16x8 wf = *(const bf16x8*)&Wt[(size_t)(cb * 16 + rl) * 64 + ks * 16 + kg * 4];
            acc[cb] = __builtin_amdgcn_mfma_f32_16x16x32_bf16(wf, xf[ks], acc[cb], 0, 0, 0);
        }
    }

    unsigned* Hrow = &H[(size_t)row * (M / 2)];
    #pragma unroll
    for (int cb = 0; cb < NCB; cb++) {
        uint2 o;
        o.x = packbf(acc[cb][0], acc[cb][1]);
        o.y = packbf(acc[cb][2], acc[cb][3]);
        *(uint2*)&Hrow[cb * 8 + kg * 2] = o;
    }
}

// ---------------- aggregation: one node per wave, readlane scalar-base gathers ----------------

__global__ __launch_bounds__(256) void agg128_kernel(const unsigned* __restrict__ H,
                                                     const int* __restrict__ cnt,
                                                     const int* __restrict__ esrc_pad,
                                                     const float* __restrict__ dinv,
                                                     const float* __restrict__ bias,
                                                     unsigned* __restrict__ out, int n) {
    int node = (blockIdx.x * blockDim.x + threadIdx.x) >> 6;
    int lane = threadIdx.x & 63;
    if (node >= n) return;
    float dn = dinv[node];
    float2 b = *(const float2*)&bias[lane * 2];
    int c = min(cnt[node], PAD);
    int s_l = (lane < c) ? esrc_pad[(size_t)node * PAD + lane] : node;
    float w_l = (lane < c) ? dinv[s_l] * dn : 0.f;
    unsigned u0 = H[(size_t)node * 64 + lane];
    float acc0 = dn * dn * bflo(u0), acc1 = dn * dn * bfhi(u0);
    for (int j = 0; j < c; j += 16) {
        unsigned u[16];
        int sr[16];
        float wr[16];
        #pragma unroll
        for (int t = 0; t < 16; t++) {
            sr[t] = __builtin_amdgcn_readlane(s_l, j + t);
            wr[t] = __uint_as_float(__builtin_amdgcn_readlane(__float_as_uint(w_l), j + t));
            u[t] = H[(size_t)sr[t] * 64 + lane];
        }
        #pragma unroll
        for (int t = 0; t < 16; t++) {
            acc0 += wr[t] * bflo(u[t]);
            acc1 += wr[t] * bfhi(u[t]);
        }
    }
    out[(size_t)node * 64 + lane] = packbf(acc0 + b.x, acc1 + b.y);
}

__global__ __launch_bounds__(256) void agg64_kernel(const unsigned short* __restrict__ H,
                                                    const int* __restrict__ cnt,
                                                    const int* __restrict__ esrc_pad,
                                                    const float* __restrict__ dinv,
                                                    const float* __restrict__ bias,
                                                    float* __restrict__ out, int n) {
    int node = (blockIdx.x * blockDim.x + threadIdx.x) >> 6;
    int lane = threadIdx.x & 63;
    if (node >= n) return;
    float dn = dinv[node];
    float bb = bias[lane];
    int c = min(cnt[node], PAD);
    int s_l = (lane < c) ? esrc_pad[(size_t)node * PAD + lane] : node;
    float w_l = (lane < c) ? dinv[s_l] * dn : 0.f;
    float acc = dn * dn * __uint_as_float(((unsigned)H[(size_t)node * 64 + lane]) << 16);
    for (int j = 0; j < c; j += 16) {
        unsigned short u[16];
        int sr[16];
        float wr[16];
        #pragma unroll
        for (int t = 0; t < 16; t++) {
            sr[t] = __builtin_amdgcn_readlane(s_l, j + t);
            wr[t] = __uint_as_float(__builtin_amdgcn_readlane(__float_as_uint(w_l), j + t));
            u[t] = H[(size_t)sr[t] * 64 + lane];
        }
        #pragma unroll
        for (int t = 0; t < 16; t++) {
            acc += wr[t] * __uint_as_float(((unsigned)u[t]) << 16);
        }
    }
    out[(size_t)node * 64 + lane] = acc + bb;
}

// ---------------- batchnorm stats ----------------

__global__ __launch_bounds__(256) void bnstats_kernel(const unsigned* __restrict__ X,
                                                      float* __restrict__ stats, int n) {
    int tid = threadIdx.x;
    int cpair = (tid & 31) * 2;
    int c0 = cpair * 2;
    int rg = tid >> 5;
    float s0 = 0, s1 = 0, s2 = 0, s3 = 0, q0 = 0, q1 = 0, q2 = 0, q3 = 0;
    int r0 = blockIdx.x * 512;
    int rend = min(r0 + 512, n);
    for (int r = r0 + rg; r < rend; r += 8) {
        uint2 u = *(const uint2*)&X[(size_t)r * 64 + cpair];
        float f0 = bflo(u.x), f1 = bfhi(u.x), f2 = bflo(u.y), f3 = bfhi(u.y);
        s0 += f0; q0 += f0 * f0;
        s1 += f1; q1 += f1 * f1;
        s2 += f2; q2 += f2 * f2;
        s3 += f3; q3 += f3 * f3;
    }
    __shared__ float ls[8][128], lq[8][128];
    ls[rg][c0] = s0; ls[rg][c0 + 1] = s1; ls[rg][c0 + 2] = s2; ls[rg][c0 + 3] = s3;
    lq[rg][c0] = q0; lq[rg][c0 + 1] = q1; lq[rg][c0 + 2] = q2; lq[rg][c0 + 3] = q3;
    __syncthreads();
    if (tid < 128) {
        float s = 0, q = 0;
        #pragma unroll
        for (int j = 0; j < 8; j++) { s += ls[j][tid]; q += lq[j][tid]; }
        atomicAdd(&stats[tid], s);
        atomicAdd(&stats[128 + tid], q);
    }
}

// ---------------- launch ----------------

extern "C" void kernel_launch(void* const* d_in, const int* in_sizes, int n_in,
                              void* d_out, int out_size, void* d_ws, size_t ws_size,
                              hipStream_t stream) {
    const float* x  = (const float*)d_in[0];
    const int*   ei = (const int*)d_in[1];
    const float* W1 = (const float*)d_in[2];
    const float* b1 = (const float*)d_in[3];
    const float* g1 = (const float*)d_in[4];
    const float* be1 = (const float*)d_in[5];
    const float* W2 = (const float*)d_in[6];
    const float* b2 = (const float*)d_in[7];
    const float* g2 = (const float*)d_in[8];
    const float* be2 = (const float*)d_in[9];
    const float* W3 = (const float*)d_in[10];
    const float* b3 = (const float*)d_in[11];
    float* out = (float*)d_out;

    const int n = N_NODES, E = N_EDGES;
    const int* src = ei;
    const int* dst = ei + E;
    const int gemmGrid = (n + 63) / 64;
    const int nbScan = (SCAN_N + 1023) / 1024;

    char* p = (char*)d_ws;
    auto alloc = [&](size_t bytes) {
        void* r = (void*)p;
        p += (bytes + 255) & ~(size_t)255;
        return r;
    };
    int*      counts   = (int*)alloc((size_t)SCAN_N * 4);
    int*      off      = (int*)alloc((size_t)(SCAN_N + 1) * 4);
    int*      bsum     = (int*)alloc((size_t)nbScan * 4);
    unsigned* ebuf     = (unsigned*)alloc((size_t)E * 4);
    int*      cnt      = (int*)alloc((size_t)n * 4);
    float*    dinv     = (float*)alloc((size_t)n * 4);
    int*      esrc_pad = (int*)alloc((size_t)n * PAD * 4);
    unsigned* Hb       = (unsigned*)alloc((size_t)n * 64 * 4);
    unsigned* Ab       = (unsigned*)alloc((size_t)n * 64 * 4);
    unsigned* Wt1      = (unsigned*)alloc(128 * 64 * 4);
    unsigned* Wt2      = (unsigned*)alloc(128 * 64 * 4);
    unsigned* Wt3      = (unsigned*)alloc(64 * 64 * 4);
    float*    stats1   = (float*)alloc(256 * 4);
    float*    stats2   = (float*)alloc(256 * 4);

    // edge partition: LDS-atomic multisplit, no global atomics
    hist_kernel<<<NBLK, 256, 0, stream>>>(dst, counts);
    scan1_kernel<<<nbScan, 1024, 0, stream>>>(counts, off, bsum, SCAN_N);
    scan2_kernel<<<1, 256, 0, stream>>>(bsum, nbScan, stats1, stats2);
    part_kernel<<<NBLK, 256, 0, stream>>>(src, dst, off, bsum, ebuf);
    bucket_kernel<<<NB, 256, 0, stream>>>(ebuf, off, bsum, esrc_pad, cnt, dinv, n);

    // weights -> bf16 transposed (single launch)
    wconv3_kernel<<<80, 256, 0, stream>>>(W1, W2, W3, Wt1, Wt2, Wt3);

    // layer 1
    gemm_mfma_kernel<128, 0><<<gemmGrid, 256, 0, stream>>>(x, Wt1, nullptr, nullptr, nullptr, Hb, n);
    agg128_kernel<<<n / 4, 256, 0, stream>>>(Hb, cnt, esrc_pad, dinv, b1, Ab, n);
    bnstats_kernel<<<(n + 511) / 512, 256, 0, stream>>>(Ab, stats1, n);

    // layer 2 (BN1 scale computed in-GEMM from stats1; BN1+ReLU fused into A-load)
    gemm_mfma_kernel<128, 1><<<gemmGrid, 256, 0, stream>>>(Ab, Wt2, stats1, g1, be1, Hb, n);
    agg128_kernel<<<n / 4, 256, 0, stream>>>(Hb, cnt, esrc_pad, dinv, b2, Ab, n);
    bnstats_kernel<<<(n + 511) / 512, 256, 0, stream>>>(Ab, stats2, n);

    // layer 3 (BN2 in-GEMM; bias b3 in agg; fp32 out)
    gemm_mfma_kernel<64, 1><<<gemmGrid, 256, 0, stream>>>(Ab, Wt3, stats2, g2, be2, Hb, n);
    agg64_kernel<<<n / 4, 256, 0, stream>>>((const unsigned short*)Hb, cnt, esrc_pad, dinv, b3, out, n);
}

// Round 10
// 322.870 us; speedup vs baseline: 2.3561x; 1.1299x over previous
//
#include <hip/hip_runtime.h>

#define N_NODES 100000
#define N_EDGES 1600000
#define PAD 48
#define NB 391                  // ceil(N_NODES/256) dst-buckets
#define NBLK 256                // partition blocks
#define EPB (N_EDGES / NBLK)    // 6250 edges per block (exact)
#define SCAN_N (NB * NBLK)      // 100096
#define NPART 64                // BN partial-stat slots

using bf16x8 = __attribute__((ext_vector_type(8))) short;
using f32x4  = __attribute__((ext_vector_type(4))) float;

// ---------------- bf16 helpers ----------------

__device__ __forceinline__ float bflo(unsigned u) { return __uint_as_float(u << 16); }
__device__ __forceinline__ float bfhi(unsigned u) { return __uint_as_float(u & 0xffff0000u); }
__device__ __forceinline__ unsigned packbf(float a, float b) {
    unsigned ua = __float_as_uint(a), ub = __float_as_uint(b);
    ua = ua + 0x7fffu + ((ua >> 16) & 1u);
    ub = ub + 0x7fffu + ((ub >> 16) & 1u);
    return (ua >> 16) | (ub & 0xffff0000u);
}

// ---------------- dispatch 1: hist + wconv3 + stats-zero ----------------
// blocks [0,256): per-chunk bucket histogram (LDS atomics only)
// blocks [256,336): weight transpose+convert  (W fp32 [128][M] -> Wt bf16 [M][128])
// blocks [336,400): zero the 64x256 partial-stat arrays

__global__ __launch_bounds__(256) void histW_kernel(const int* __restrict__ dst,
                                                    int* __restrict__ counts,
                                                    const float* __restrict__ W1,
                                                    const float* __restrict__ W2,
                                                    const float* __restrict__ W3,
                                                    unsigned* __restrict__ Wt1,
                                                    unsigned* __restrict__ Wt2,
                                                    unsigned* __restrict__ Wt3,
                                                    float* __restrict__ stats1,
                                                    float* __restrict__ stats2) {
    __shared__ int hist[NB];
    int tid = threadIdx.x, b = blockIdx.x;
    if (b < 256) {
        for (int i = tid; i < NB; i += 256) hist[i] = 0;
        __syncthreads();
        int s0 = b * EPB;
        for (int k = tid; k < EPB; k += 256)
            atomicAdd(&hist[dst[s0 + k] >> 8], 1);
        __syncthreads();
        for (int bb = tid; bb < NB; bb += 256) counts[bb * NBLK + b] = hist[bb];
    } else if (b < 336) {
        int wb = b - 256;
        const float* W;
        unsigned* Wt;
        int M, i;
        if (wb < 32)      { W = W1; Wt = Wt1; M = 128; i = wb * 256 + tid; }
        else if (wb < 64) { W = W2; Wt = Wt2; M = 128; i = (wb - 32) * 256 + tid; }
        else              { W = W3; Wt = Wt3; M = 64;  i = (wb - 64) * 256 + tid; }
        if (i < M * 64) {
            int m = i >> 6, ku = i & 63;
            Wt[(size_t)m * 64 + ku] =
                packbf(W[(size_t)(2 * ku) * M + m], W[(size_t)(2 * ku + 1) * M + m]);
        }
    } else {
        int i = (b - 336) * 256 + tid;  // 64 blocks x 256 = 16384 = NPART*256
        stats1[i] = 0.f;
        stats2[i] = 0.f;
    }
}

// ---------------- scan phase 1 ----------------

__global__ __launch_bounds__(1024) void scan1_kernel(const int* __restrict__ cnt,
                                                     int* __restrict__ off,
                                                     int* __restrict__ bsum, int n) {
    __shared__ int wsum[17];
    int tid = threadIdx.x, lane = tid & 63, w = tid >> 6;
    int i = blockIdx.x * 1024 + tid;
    int v = (i < n) ? cnt[i] : 0;
    int x = v;
    #pragma unroll
    for (int d = 1; d < 64; d <<= 1) {
        int y = __shfl_up(x, d, 64);
        if (lane >= d) x += y;
    }
    if (lane == 63) wsum[w] = x;
    __syncthreads();
    if (tid == 0) {
        int s = 0;
        #pragma unroll
        for (int j = 0; j < 16; j++) { int t = wsum[j]; wsum[j] = s; s += t; }
        wsum[16] = s;
    }
    __syncthreads();
    if (i < n) off[i + 1] = x + wsum[w];
    if (tid == 0) bsum[blockIdx.x] = wsum[16];
}

// ---------------- scan phase 2: parallel exclusive scan of bsum[98] ----------------

__global__ void scan2p_kernel(int* __restrict__ bsum, int nb) {
    __shared__ int tmp[128];
    int t = threadIdx.x;  // 128
    int v = (t < nb) ? bsum[t] : 0;
    tmp[t] = v;
    __syncthreads();
    #pragma unroll
    for (int d = 1; d < 128; d <<= 1) {
        int u = (t >= d) ? tmp[t - d] : 0;
        __syncthreads();
        tmp[t] += u;
        __syncthreads();
    }
    if (t < nb) bsum[t] = tmp[t] - v;  // exclusive
}

__device__ __forceinline__ int off_at(const int* __restrict__ off_raw,
                                      const int* __restrict__ bsum, int idx) {
    return idx ? off_raw[idx] + bsum[(idx - 1) >> 10] : 0;
}

// ---------------- dispatch 4: part + gemm1 (MODE0) ----------------
// blocks [0,256): scatter edges into bucket-major ebuf (packed src | local_dst<<17)
// blocks [256, 256+1563): layer-1 MFMA GEMM (fp32 x -> bf16 H)

__global__ __launch_bounds__(256) void partG1_kernel(const int* __restrict__ src,
                                                     const int* __restrict__ dst,
                                                     const int* __restrict__ off_raw,
                                                     const int* __restrict__ bsum,
                                                     unsigned* __restrict__ ebuf,
                                                     const float* __restrict__ X,
                                                     const unsigned* __restrict__ Wt,
                                                     unsigned* __restrict__ H, int n) {
    __shared__ int cur[NB];
    int tid = threadIdx.x;
    if (blockIdx.x < NBLK) {
        int blk = blockIdx.x;
        for (int b = tid; b < NB; b += 256)
            cur[b] = off_at(off_raw, bsum, b * NBLK + blk);
        __syncthreads();
        int s0 = blk * EPB;
        for (int k = tid; k < EPB; k += 256) {
            int s = src[s0 + k], d = dst[s0 + k];
            int pos = atomicAdd(&cur[d >> 8], 1);
            ebuf[pos] = (unsigned)s | ((unsigned)(d & 255) << 17);
        }
        return;
    }
    int gb = blockIdx.x - NBLK;
    int wid = tid >> 6, lane = tid & 63;
    int r0 = (gb * 4 + wid) * 16;
    if (r0 >= n) return;
    int rl = lane & 15, kg = lane >> 4;
    int row = r0 + rl;
    bf16x8 xf[4];
    #pragma unroll
    for (int ks = 0; ks < 4; ks++) {
        const float* p = &X[(size_t)row * 128 + ks * 32 + kg * 8];
        float4 f0 = *(const float4*)p;
        float4 f1 = *(const float4*)(p + 4);
        unsigned o[4] = { packbf(f0.x, f0.y), packbf(f0.z, f0.w),
                          packbf(f1.x, f1.y), packbf(f1.z, f1.w) };
        xf[ks] = *(bf16x8*)o;
    }
    f32x4 acc[8];
    #pragma unroll
    for (int cb = 0; cb < 8; cb++) acc[cb] = (f32x4){0.f, 0.f, 0.f, 0.f};
    #pragma unroll
    for (int cb = 0; cb < 8; cb++) {
        #pragma unroll
        for (int ks = 0; ks < 4; ks++) {
            bf16x8 wf = *(const bf16x8*)&Wt[(size_t)(cb * 16 + rl) * 64 + ks * 16 + kg * 4];
            acc[cb] = __builtin_amdgcn_mfma_f32_16x16x32_bf16(wf, xf[ks], acc[cb], 0, 0, 0);
        }
    }
    unsigned* Hrow = &H[(size_t)row * 64];
    #pragma unroll
    for (int cb = 0; cb < 8; cb++) {
        uint2 o;
        o.x = packbf(acc[cb][0], acc[cb][1]);
        o.y = packbf(acc[cb][2], acc[cb][3]);
        *(uint2*)&Hrow[cb * 8 + kg * 2] = o;
    }
}

// ---------------- bucket: padded-CSR slab in LDS, coalesced copy out ----------------

__global__ __launch_bounds__(256) void bucket_kernel(const unsigned* __restrict__ ebuf,
                                                     const int* __restrict__ off_raw,
                                                     const int* __restrict__ bsum,
                                                     int* __restrict__ esrc_pad,
                                                     int* __restrict__ cnt,
                                                     float* __restrict__ dinv, int n) {
    __shared__ int epad[256 * PAD];
    __shared__ int cur[256];
    int tid = threadIdx.x, b = blockIdx.x;
    int start = off_at(off_raw, bsum, b * NBLK);
    int end = off_at(off_raw, bsum, (b + 1) * NBLK);
    cur[tid] = 0;
    __syncthreads();
    for (int e = start + tid; e < end; e += 256) {
        unsigned sd = ebuf[e];
        int ld = sd >> 17;
        int pos = atomicAdd(&cur[ld], 1);
        if (pos < PAD) epad[ld * PAD + pos] = (int)(sd & 0x1FFFFu);
    }
    __syncthreads();
    int nd0 = b << 8;
    int nn = min(256, n - nd0);
    if (tid < nn) {
        cnt[nd0 + tid] = cur[tid];
        dinv[nd0 + tid] = rsqrtf((float)(cur[tid] + 1));  // +1 self-loop
    }
    int tot = nn * PAD;
    for (int i = tid; i < tot; i += 256) esrc_pad[(size_t)nd0 * PAD + i] = epad[i];
}

// ---------------- MFMA GEMM layers 2/3: bf16 in + fused BN+ReLU ----------------
// BN scale/shift computed in-block from the 64 partial-stat slots.

template <int M>
__global__ __launch_bounds__(256) void gemmB_mfma_kernel(const unsigned* __restrict__ X,
                                                         const unsigned* __restrict__ Wt,
                                                         const float* __restrict__ stats,
                                                         const float* __restrict__ g,
                                                         const float* __restrict__ be,
                                                         unsigned* __restrict__ H, int n) {
    __shared__ float sls[256];  // [0:128) scale, [128:256) shift
    {
        int t = threadIdx.x;
        if (t < 128) {
            float s = 0.f, q = 0.f;
            #pragma unroll 8
            for (int p2 = 0; p2 < NPART; p2++) {
                s += stats[p2 * 256 + t];
                q += stats[p2 * 256 + 128 + t];
            }
            float inv_n = 1.f / (float)n;
            float mu = s * inv_n;
            float var = q * inv_n - mu * mu;
            float sc = g[t] * rsqrtf(var + 1e-5f);
            sls[t] = sc;
            sls[128 + t] = be[t] - mu * sc;
        }
        __syncthreads();
    }
    int wid = threadIdx.x >> 6, lane = threadIdx.x & 63;
    int r0 = (blockIdx.x * 4 + wid) * 16;
    if (r0 >= n) return;
    int rl = lane & 15, kg = lane >> 4;
    int row = r0 + rl;

    bf16x8 xf[4];
    #pragma unroll
    for (int ks = 0; ks < 4; ks++) {
        int c = ks * 32 + kg * 8;
        uint4 u = *(const uint4*)&X[(size_t)row * 64 + (c >> 1)];
        float4 sc0 = *(const float4*)&sls[c];
        float4 sc1 = *(const float4*)&sls[c + 4];
        float4 sh0 = *(const float4*)&sls[128 + c];
        float4 sh1 = *(const float4*)&sls[128 + c + 4];
        float v0 = fmaxf(bflo(u.x) * sc0.x + sh0.x, 0.f);
        float v1 = fmaxf(bfhi(u.x) * sc0.y + sh0.y, 0.f);
        float v2 = fmaxf(bflo(u.y) * sc0.z + sh0.z, 0.f);
        float v3 = fmaxf(bfhi(u.y) * sc0.w + sh0.w, 0.f);
        float v4 = fmaxf(bflo(u.z) * sc1.x + sh1.x, 0.f);
        float v5 = fmaxf(bfhi(u.z) * sc1.y + sh1.y, 0.f);
        float v6 = fmaxf(bflo(u.w) * sc1.z + sh1.z, 0.f);
        float v7 = fmaxf(bfhi(u.w) * sc1.w + sh1.w, 0.f);
        unsigned o[4] = { packbf(v0, v1), packbf(v2, v3), packbf(v4, v5), packbf(v6, v7) };
        xf[ks] = *(bf16x8*)o;
    }

    constexpr int NCB = M / 16;
    f32x4 acc[NCB];
    #pragma unroll
    for (int cb = 0; cb < NCB; cb++) acc[cb] = (f32x4){0.f, 0.f, 0.f, 0.f};
    #pragma unroll
    for (int cb = 0; cb < NCB; cb++) {
        #pragma unroll
        for (int ks = 0; ks < 4; ks++) {
            bf16x8 wf = *(const bf16x8*)&Wt[(size_t)(cb * 16 + rl) * 64 + ks * 16 + kg * 4];
            acc[cb] = __builtin_amdgcn_mfma_f32_16x16x32_bf16(wf, xf[ks], acc[cb], 0, 0, 0);
        }
    }
    unsigned* Hrow = &H[(size_t)row * (M / 2)];
    #pragma unroll
    for (int cb = 0; cb < NCB; cb++) {
        uint2 o;
        o.x = packbf(acc[cb][0], acc[cb][1]);
        o.y = packbf(acc[cb][2], acc[cb][3]);
        *(uint2*)&Hrow[cb * 8 + kg * 2] = o;
    }
}

// ---------------- aggregation + BN partial stats (one node per wave) ----------------
// Grid is exactly n/4 (n % 4 == 0): no partial blocks, all threads reach barriers.

__global__ __launch_bounds__(256) void agg128bn_kernel(const unsigned* __restrict__ H,
                                                       const int* __restrict__ cnt,
                                                       const int* __restrict__ esrc_pad,
                                                       const float* __restrict__ dinv,
                                                       const float* __restrict__ bias,
                                                       unsigned* __restrict__ out,
                                                       float* __restrict__ stats) {
    int node = (blockIdx.x * blockDim.x + threadIdx.x) >> 6;
    int lane = threadIdx.x & 63;
    int wv = threadIdx.x >> 6;
    float dn = dinv[node];
    float2 b = *(const float2*)&bias[lane * 2];
    int c = min(cnt[node], PAD);
    int s_l = (lane < c) ? esrc_pad[(size_t)node * PAD + lane] : node;
    float w_l = (lane < c) ? dinv[s_l] * dn : 0.f;
    unsigned u0 = H[(size_t)node * 64 + lane];
    float acc0 = dn * dn * bflo(u0), acc1 = dn * dn * bfhi(u0);
    for (int j = 0; j < c; j += 16) {
        unsigned u[16];
        int sr[16];
        float wr[16];
        #pragma unroll
        for (int t = 0; t < 16; t++) {
            sr[t] = __builtin_amdgcn_readlane(s_l, j + t);
            wr[t] = __uint_as_float(__builtin_amdgcn_readlane(__float_as_uint(w_l), j + t));
            u[t] = H[(size_t)sr[t] * 64 + lane];
        }
        #pragma unroll
        for (int t = 0; t < 16; t++) {
            acc0 += wr[t] * bflo(u[t]);
            acc1 += wr[t] * bfhi(u[t]);
        }
    }
    float o0 = acc0 + b.x, o1 = acc1 + b.y;
    out[(size_t)node * 64 + lane] = packbf(o0, o1);
    // BN partial stats: block reduce -> one atomicAdd pair per column into slot (blk&63)
    __shared__ float ls[4][128], lq[4][128];
    ls[wv][lane * 2] = o0;
    ls[wv][lane * 2 + 1] = o1;
    lq[wv][lane * 2] = o0 * o0;
    lq[wv][lane * 2 + 1] = o1 * o1;
    __syncthreads();
    int t = threadIdx.x;
    if (t < 128) {
        float s = ls[0][t] + ls[1][t] + ls[2][t] + ls[3][t];
        float q = lq[0][t] + lq[1][t] + lq[2][t] + lq[3][t];
        float* sp = &stats[(blockIdx.x & (NPART - 1)) * 256];
        atomicAdd(&sp[t], s);
        atomicAdd(&sp[128 + t], q);
    }
}

__global__ __launch_bounds__(256) void agg64_kernel(const unsigned short* __restrict__ H,
                                                    const int* __restrict__ cnt,
                                                    const int* __restrict__ esrc_pad,
                                                    const float* __restrict__ dinv,
                                                    const float* __restrict__ bias,
                                                    float* __restrict__ out, int n) {
    int node = (blockIdx.x * blockDim.x + threadIdx.x) >> 6;
    int lane = threadIdx.x & 63;
    if (node >= n) return;
    float dn = dinv[node];
    float bb = bias[lane];
    int c = min(cnt[node], PAD);
    int s_l = (lane < c) ? esrc_pad[(size_t)node * PAD + lane] : node;
    float w_l = (lane < c) ? dinv[s_l] * dn : 0.f;
    float acc = dn * dn * __uint_as_float(((unsigned)H[(size_t)node * 64 + lane]) << 16);
    for (int j = 0; j < c; j += 16) {
        unsigned short u[16];
        int sr[16];
        float wr[16];
        #pragma unroll
        for (int t = 0; t < 16; t++) {
            sr[t] = __builtin_amdgcn_readlane(s_l, j + t);
            wr[t] = __uint_as_float(__builtin_amdgcn_readlane(__float_as_uint(w_l), j + t));
            u[t] = H[(size_t)sr[t] * 64 + lane];
        }
        #pragma unroll
        for (int t = 0; t < 16; t++) {
            acc += wr[t] * __uint_as_float(((unsigned)u[t]) << 16);
        }
    }
    out[(size_t)node * 64 + lane] = acc + bb;
}

// ---------------- launch ----------------

extern "C" void kernel_launch(void* const* d_in, const int* in_sizes, int n_in,
                              void* d_out, int out_size, void* d_ws, size_t ws_size,
                              hipStream_t stream) {
    const float* x  = (const float*)d_in[0];
    const int*   ei = (const int*)d_in[1];
    const float* W1 = (const float*)d_in[2];
    const float* b1 = (const float*)d_in[3];
    const float* g1 = (const float*)d_in[4];
    const float* be1 = (const float*)d_in[5];
    const float* W2 = (const float*)d_in[6];
    const float* b2 = (const float*)d_in[7];
    const float* g2 = (const float*)d_in[8];
    const float* be2 = (const float*)d_in[9];
    const float* W3 = (const float*)d_in[10];
    const float* b3 = (const float*)d_in[11];
    float* out = (float*)d_out;

    const int n = N_NODES, E = N_EDGES;
    const int* src = ei;
    const int* dst = ei + E;
    const int gemmGrid = (n + 63) / 64;
    const int nbScan = (SCAN_N + 1023) / 1024;  // 98

    char* p = (char*)d_ws;
    auto alloc = [&](size_t bytes) {
        void* r = (void*)p;
        p += (bytes + 255) & ~(size_t)255;
        return r;
    };
    int*      counts   = (int*)alloc((size_t)SCAN_N * 4);
    int*      off      = (int*)alloc((size_t)(SCAN_N + 1) * 4);
    int*      bsum     = (int*)alloc((size_t)nbScan * 4);
    unsigned* ebuf     = (unsigned*)alloc((size_t)E * 4);
    int*      cnt      = (int*)alloc((size_t)n * 4);
    float*    dinv     = (float*)alloc((size_t)n * 4);
    int*      esrc_pad = (int*)alloc((size_t)n * PAD * 4);
    unsigned* Hb       = (unsigned*)alloc((size_t)n * 64 * 4);
    unsigned* Ab       = (unsigned*)alloc((size_t)n * 64 * 4);
    unsigned* Wt1      = (unsigned*)alloc(128 * 64 * 4);
    unsigned* Wt2      = (unsigned*)alloc(128 * 64 * 4);
    unsigned* Wt3      = (unsigned*)alloc(64 * 64 * 4);
    float*    stats1   = (float*)alloc((size_t)NPART * 256 * 4);
    float*    stats2   = (float*)alloc((size_t)NPART * 256 * 4);

    // 1: hist + weight convert + stats zero
    histW_kernel<<<400, 256, 0, stream>>>(dst, counts, W1, W2, W3, Wt1, Wt2, Wt3,
                                          stats1, stats2);
    // 2-3: scan
    scan1_kernel<<<nbScan, 1024, 0, stream>>>(counts, off, bsum, SCAN_N);
    scan2p_kernel<<<1, 128, 0, stream>>>(bsum, nbScan);
    // 4: edge scatter + layer-1 GEMM
    partG1_kernel<<<NBLK + gemmGrid, 256, 0, stream>>>(src, dst, off, bsum, ebuf,
                                                       x, Wt1, Hb, n);
    // 5: padded-CSR build
    bucket_kernel<<<NB, 256, 0, stream>>>(ebuf, off, bsum, esrc_pad, cnt, dinv, n);

    // 6: layer-1 aggregation + BN1 partial stats
    agg128bn_kernel<<<n / 4, 256, 0, stream>>>(Hb, cnt, esrc_pad, dinv, b1, Ab, stats1);
    // 7: layer-2 GEMM (BN1 finalize in-block)
    gemmB_mfma_kernel<128><<<gemmGrid, 256, 0, stream>>>(Ab, Wt2, stats1, g1, be1, Hb, n);
    // 8: layer-2 aggregation + BN2 partial stats
    agg128bn_kernel<<<n / 4, 256, 0, stream>>>(Hb, cnt, esrc_pad, dinv, b2, Ab, stats2);
    // 9: layer-3 GEMM (BN2 finalize in-block)
    gemmB_mfma_kernel<64><<<gemmGrid, 256, 0, stream>>>(Ab, Wt3, stats2, g2, be2, Hb, n);
    // 10: layer-3 aggregation (bias b3, fp32 out)
    agg64_kernel<<<n / 4, 256, 0, stream>>>((const unsigned short*)Hb, cnt, esrc_pad,
                                            dinv, b3, out, n);
}